// Round 8
// baseline (290.039 us; speedup 1.0000x reference)
//
#include <hip/hip_runtime.h>

// GCN: N=100000, E=800000, D=128, two GraphConv layers.
// R12 = R11 (best: 267.5us) + two separable changes:
//  A) gather: ONE NODE PER 64-LANE WAVE (4 edge-slots x 16 lanes) instead of
//     4 nodes per wave. Removes cross-node lockstep (wave loop was
//     max(ceil(deg/4)) over 4 nodes ~ 3.2 iters vs 2.3 needed for
//     Poisson(8) degrees); cross-slot sum via shfl_xor(16/32). 100K waves.
//  B) gemm: 2 adjacent tiles per wave; B-fragment LDS read shared by both
//     MFMAs; 782 blocks (half the wb staging + block overhead).
// Everything else identical to R11 (LDS-histogram CSR build, bf16 wb
// staged to LDS, zero global atomics).

#define NN 100000
#define EE 800000
#define DD 128
#define NB1 98            // ceil(NN / 1024) blocks for scan level 1
#define NTILE (NN / 16)   // 6250 MFMA row-tiles (NN % 16 == 0)

#define CC 64             // edge chunks
#define CH (EE / CC)      // 12500 edges per chunk
#define HALF 50000        // nodes per LDS histogram (2 ranges)
#define HWORDS 12500      // packed u8 words per histogram (50KB LDS)
#define NWORDS 25000      // packed words per full node array

typedef __attribute__((ext_vector_type(8))) short short8;
typedef __attribute__((ext_vector_type(4))) float floatx4;

__device__ inline float bf2f(unsigned int u16) {
    union { unsigned int i; float f; } c;
    c.i = u16 << 16;
    return c.f;
}
__device__ inline ushort f2bf(float f) {
    union { float f; unsigned int i; } c;
    c.f = f;
    unsigned int u = c.i;
    return (ushort)((u + 0x7fffu + ((u >> 16) & 1u)) >> 16);  // RNE
}

// ---------------- chunked packed-u8 LDS histograms ----------------
__global__ __launch_bounds__(512) void count_kernel(const int* __restrict__ row,
                                                    const int* __restrict__ col,
                                                    unsigned int* __restrict__ partial_out,
                                                    unsigned int* __restrict__ partial_in,
                                                    unsigned char* __restrict__ off_u8) {
    __shared__ unsigned int h[HWORDS];
    for (int i = threadIdx.x; i < HWORDS; i += 512) h[i] = 0;
    __syncthreads();

    const int kind = blockIdx.x >> 7;          // 0 = in (col), 1 = out (row)
    const int r = (blockIdx.x >> 6) & 1;       // node range
    const int c = blockIdx.x & 63;             // edge chunk
    const int* __restrict__ idx = kind ? row : col;
    const int base = c * CH;
    const int lo = r * HALF;

    for (int t = threadIdx.x; t < CH; t += 512) {
        const int e = base + t;
        const unsigned int d = (unsigned int)(idx[e] - lo);
        if (d < (unsigned int)HALF) {
            const int sh = 8 * (d & 3);
            unsigned int old = atomicAdd(&h[d >> 2], 1u << sh);
            if (kind == 0) off_u8[e] = (unsigned char)((old >> sh) & 0xffu);
        }
    }
    __syncthreads();

    unsigned int* dst = (kind ? partial_out : partial_in) + c * NWORDS + r * HWORDS;
    for (int i = threadIdx.x; i < HWORDS; i += 512) dst[i] = h[i];
}

// ---------------- per-node: totals, dinv, per-chunk packed-u8 prefixes ----------------
__global__ __launch_bounds__(256) void node_kernel(const unsigned int* __restrict__ partial_out,
                                                   const unsigned int* __restrict__ partial_in,
                                                   int* __restrict__ cnt_total,
                                                   unsigned int* __restrict__ xoff,
                                                   float* __restrict__ dinv_out,
                                                   float* __restrict__ dinv_in) {
    const int w = blockIdx.x * 256 + threadIdx.x;
    if (w >= NWORDS) return;
    unsigned int prefix = 0;   // packed running prefix (4 nodes)
    unsigned int tot_out = 0;  // packed out-degree totals
#pragma unroll
    for (int c = 0; c < CC; ++c) {
        unsigned int v = partial_in[c * NWORDS + w];
        xoff[c * NWORDS + w] = prefix;
        prefix += v;
        tot_out += partial_out[c * NWORDS + w];
    }
    int4 ct;
    float4 fi, fo;
#pragma unroll
    for (int j = 0; j < 4; ++j) {
        int din  = (int)((prefix  >> (8 * j)) & 0xffu);
        int dout = (int)((tot_out >> (8 * j)) & 0xffu);
        ((int*)&ct)[j]   = din;
        ((float*)&fi)[j] = rsqrtf((float)max(din, 1));
        ((float*)&fo)[j] = rsqrtf((float)max(dout, 1));
    }
    ((int4*)cnt_total)[w] = ct;
    ((float4*)dinv_in)[w] = fi;
    ((float4*)dinv_out)[w] = fo;
}

// ---------------- exclusive scan of cnt_total (3-level) ----------------
__global__ __launch_bounds__(256) void scan1_kernel(const int* __restrict__ cnt,
                                                    int* __restrict__ excl,
                                                    int* __restrict__ bsums) {
    __shared__ int tmp[256];
    const int t = threadIdx.x;
    const int base = blockIdx.x * 1024 + t * 4;
    int a[4];
#pragma unroll
    for (int q = 0; q < 4; ++q) a[q] = (base + q < NN) ? cnt[base + q] : 0;
    int s = a[0] + a[1] + a[2] + a[3];
    tmp[t] = s;
    __syncthreads();
    for (int off = 1; off < 256; off <<= 1) {
        int v = 0;
        if (t >= off) v = tmp[t - off];
        __syncthreads();
        tmp[t] += v;
        __syncthreads();
    }
    int excl_s = tmp[t] - s;
    if (t == 255) bsums[blockIdx.x] = tmp[t];
    int run = excl_s;
#pragma unroll
    for (int q = 0; q < 4; ++q) {
        if (base + q < NN) excl[base + q] = run;
        run += a[q];
    }
}

__global__ __launch_bounds__(256) void scan2_kernel(int* __restrict__ bsums, int nb) {
    __shared__ int tmp[256];
    const int t = threadIdx.x;
    int s = (t < nb) ? bsums[t] : 0;
    tmp[t] = s;
    __syncthreads();
    for (int off = 1; off < 256; off <<= 1) {
        int v = 0;
        if (t >= off) v = tmp[t - off];
        __syncthreads();
        tmp[t] += v;
        __syncthreads();
    }
    if (t < nb) bsums[t] = tmp[t] - s;   // exclusive
}

__global__ __launch_bounds__(256) void scan3_kernel(const int* __restrict__ excl,
                                                    const int* __restrict__ bsums,
                                                    int* __restrict__ row_start) {
    int i = blockIdx.x * 256 + threadIdx.x;
    if (i < NN) row_start[i] = excl[i] + bsums[i >> 10];
}

// ---------------- atomic-free CSR fill ----------------
__global__ __launch_bounds__(256) void fill_kernel(const int* __restrict__ row,
                                                   const int* __restrict__ col,
                                                   const int* __restrict__ row_start,
                                                   const unsigned char* __restrict__ xoff_u8,
                                                   const unsigned char* __restrict__ off_u8,
                                                   int* __restrict__ srcs) {
    int e = blockIdx.x * 256 + threadIdx.x;
    if (e < EE) {
        const int cl = col[e];
        const int c = e / CH;                    // chunk id
        const int pos = row_start[cl] + (int)xoff_u8[(size_t)c * NN + cl] + (int)off_u8[e];
        srcs[pos] = row[e];
    }
}

// ---------------- xb = bf16(x * dinv_out) ----------------
__global__ __launch_bounds__(256) void prescale_kernel(const float* __restrict__ x,
                                                       const float* __restrict__ dinv_out,
                                                       ushort* __restrict__ xb) {
    int idx = blockIdx.x * 256 + threadIdx.x;   // one float4 per thread
    if (idx >= NN * 32) return;
    int n = idx >> 5;
    float s = dinv_out[n];
    float4 v = ((const float4*)x)[idx];
    ushort4 o;
    o.x = f2bf(v.x * s);
    o.y = f2bf(v.y * s);
    o.z = f2bf(v.z * s);
    o.w = f2bf(v.w * s);
    ((ushort4*)xb)[idx] = o;
}

// ---------------- W fp32 -> bf16 (once, both layers) ----------------
__global__ __launch_bounds__(256) void wconv_kernel(const float* __restrict__ W1,
                                                    const float* __restrict__ W2,
                                                    ushort* __restrict__ wb1,
                                                    ushort* __restrict__ wb2) {
    int i = blockIdx.x * 256 + threadIdx.x;     // one float4 per thread, 2*4096 total
    if (i >= 8192) return;
    const float* W = (i < 4096) ? W1 : W2;
    ushort* wb = (i < 4096) ? wb1 : wb2;
    int j = i & 4095;
    float4 v = ((const float4*)W)[j];
    ushort4 o;
    o.x = f2bf(v.x); o.y = f2bf(v.y); o.z = f2bf(v.z); o.w = f2bf(v.w);
    ((ushort4*)wb)[j] = o;
}

// ---------------- gather: 1 node per 64-lane wave, 4 edge-slots x 16 lanes ----------------
__global__ __launch_bounds__(256) void gather_kernel(const ushort* __restrict__ src,
                                                     const int* __restrict__ row_start,
                                                     const int* __restrict__ srcs,
                                                     ushort* __restrict__ agg) {
    const int node = blockIdx.x * 4 + (threadIdx.x >> 6);
    const int lane = threadIdx.x & 63;
    const int slot = lane >> 4;        // edge slot 0..3
    const int lane16 = lane & 15;      // 16B chunk within a 256B row
    // NN % 4 == 0 and grid == NN/4, so node < NN always.
    int p = row_start[node];
    const int end = (node + 1 < NN) ? row_start[node + 1] : EE;
    float a0 = 0.f, a1 = 0.f, a2 = 0.f, a3 = 0.f;
    float a4 = 0.f, a5 = 0.f, a6 = 0.f, a7 = 0.f;

#define ACCUM(V)                                     \
    do {                                             \
        a0 += bf2f((V).x & 0xffffu);                 \
        a1 += bf2f((V).x >> 16);                     \
        a2 += bf2f((V).y & 0xffffu);                 \
        a3 += bf2f((V).y >> 16);                     \
        a4 += bf2f((V).z & 0xffffu);                 \
        a5 += bf2f((V).z >> 16);                     \
        a6 += bf2f((V).w & 0xffffu);                 \
        a7 += bf2f((V).w >> 16);                     \
    } while (0)

    for (; p + 8 <= end; p += 8) {                   // 8 edges per wave-iter
        int sA = srcs[p + slot];
        int sB = srcs[p + 4 + slot];
        uint4 vA = ((const uint4*)(src + (size_t)sA * DD))[lane16];
        uint4 vB = ((const uint4*)(src + (size_t)sB * DD))[lane16];
        ACCUM(vA); ACCUM(vB);
    }
    if (p + 4 <= end) {                              // 4-edge batch
        int sA = srcs[p + slot];
        uint4 vA = ((const uint4*)(src + (size_t)sA * DD))[lane16];
        ACCUM(vA);
        p += 4;
    }
    if (p + slot < end) {                            // masked tail (0..3 edges)
        int sA = srcs[p + slot];
        uint4 vA = ((const uint4*)(src + (size_t)sA * DD))[lane16];
        ACCUM(vA);
    }
#undef ACCUM

    // sum across the 4 edge slots (lanes L, L^16, L^32, L^48)
    a0 += __shfl_xor(a0, 16, 64); a0 += __shfl_xor(a0, 32, 64);
    a1 += __shfl_xor(a1, 16, 64); a1 += __shfl_xor(a1, 32, 64);
    a2 += __shfl_xor(a2, 16, 64); a2 += __shfl_xor(a2, 32, 64);
    a3 += __shfl_xor(a3, 16, 64); a3 += __shfl_xor(a3, 32, 64);
    a4 += __shfl_xor(a4, 16, 64); a4 += __shfl_xor(a4, 32, 64);
    a5 += __shfl_xor(a5, 16, 64); a5 += __shfl_xor(a5, 32, 64);
    a6 += __shfl_xor(a6, 16, 64); a6 += __shfl_xor(a6, 32, 64);
    a7 += __shfl_xor(a7, 16, 64); a7 += __shfl_xor(a7, 32, 64);

    if (slot == 0) {
        uint4 o;
        o.x = (unsigned int)f2bf(a0) | ((unsigned int)f2bf(a1) << 16);
        o.y = (unsigned int)f2bf(a2) | ((unsigned int)f2bf(a3) << 16);
        o.z = (unsigned int)f2bf(a4) | ((unsigned int)f2bf(a5) << 16);
        o.w = (unsigned int)f2bf(a6) | ((unsigned int)f2bf(a7) << 16);
        ((uint4*)(agg + (size_t)node * DD))[lane16] = o;
    }
}

// ---------------- MFMA bf16 GEMM + epilogue ----------------
// C[m, j] = sum_k agg[m,k] * wb[j,k]   (wb row-major [j][k] == B^T input)
// Block: 256 threads = 4 waves; each wave TWO adjacent 16-row tiles, B-frag
// LDS read shared by both MFMAs. wb staged to LDS, rows padded to 136.
template <bool L1>
__global__ __launch_bounds__(256) void gemm_ep(const ushort* __restrict__ agg,
                                               const ushort* __restrict__ wb,
                                               const float* __restrict__ bias,
                                               const float* __restrict__ dinv_in,
                                               const float* __restrict__ dinv_out,
                                               const float* __restrict__ x,
                                               ushort* __restrict__ hs,
                                               float* __restrict__ out) {
    __shared__ ushort Ws[128 * 136];
    {   // stage wb (already bf16) into LDS: 128B per thread = 8 x uint4
        int j = threadIdx.x >> 1;
        int k0 = (threadIdx.x & 1) * 64;
        const uint4* wp = (const uint4*)(wb + (size_t)j * DD + k0);
        uint4* dst = (uint4*)(Ws + j * 136 + k0);
#pragma unroll
        for (int q = 0; q < 8; ++q) dst[q] = wp[q];
    }
    __syncthreads();

    const int wave = threadIdx.x >> 6;
    const int lane = threadIdx.x & 63;
    const int tbase = blockIdx.x * 8 + wave * 2;     // first of 2 tiles
    if (tbase >= NTILE) return;                       // uniform per wave; after barrier
    const int mi = lane & 15;
    const int quad = lane >> 4;

    floatx4 acc[2][8];
#pragma unroll
    for (int u = 0; u < 2; ++u)
#pragma unroll
        for (int t = 0; t < 8; ++t) acc[u][t] = (floatx4){0.f, 0.f, 0.f, 0.f};

    const ushort* ap0 = agg + (size_t)(tbase * 16 + mi) * DD + quad * 8;
    const ushort* ap1 = ap0 + (size_t)16 * DD;       // tile tbase+1 (may read past
                                                     // agg into xb for the last
                                                     // guarded tile: harmless)
#pragma unroll
    for (int s = 0; s < 4; ++s) {
        short8 A0 = *(const short8*)(ap0 + s * 32);
        short8 A1 = *(const short8*)(ap1 + s * 32);
#pragma unroll
        for (int t = 0; t < 8; ++t) {
            short8 b = *(const short8*)(Ws + (t * 16 + mi) * 136 + s * 32 + quad * 8);
            acc[0][t] = __builtin_amdgcn_mfma_f32_16x16x32_bf16(A0, b, acc[0][t], 0, 0, 0);
            acc[1][t] = __builtin_amdgcn_mfma_f32_16x16x32_bf16(A1, b, acc[1][t], 0, 0, 0);
        }
    }

    // C/D layout: col = lane&15, row = quad*4 + reg
#pragma unroll
    for (int u = 0; u < 2; ++u) {
        const int tile = tbase + u;
        if (tile >= NTILE) break;
        const int m0 = tile * 16;
        float dv[4], dov[4];
#pragma unroll
        for (int i = 0; i < 4; ++i) {
            int r = m0 + quad * 4 + i;
            dv[i] = dinv_in[r];
            if (L1) dov[i] = dinv_out[r];
        }
#pragma unroll
        for (int t = 0; t < 8; ++t) {
            int c = t * 16 + mi;
            float bv = bias[c];
#pragma unroll
            for (int i = 0; i < 4; ++i) {
                int r = m0 + quad * 4 + i;
                float o = (acc[u][t][i] + bv) * dv[i];
                if (L1) {
                    o += x[(size_t)r * DD + c];
                    o = fmaxf(o, 0.f);
                    hs[(size_t)r * DD + c] = f2bf(o * dov[i]);
                } else {
                    out[(size_t)r * DD + c] = o;
                }
            }
        }
    }
}

extern "C" void kernel_launch(void* const* d_in, const int* in_sizes, int n_in,
                              void* d_out, int out_size, void* d_ws, size_t ws_size,
                              hipStream_t stream) {
    const float* x  = (const float*)d_in[0];
    const int*   ei = (const int*)d_in[1];
    const float* W1 = (const float*)d_in[2];
    const float* b1 = (const float*)d_in[3];
    const float* W2 = (const float*)d_in[4];
    const float* b2 = (const float*)d_in[5];
    float* out = (float*)d_out;

    const int* row = ei;        // edge_index[0] (source)
    const int* col = ei + EE;   // edge_index[1] (target)

    // workspace layout. The agg region (25.6MB) hosts the CSR-build
    // temporaries (off_u8 0.8MB, partial_in/out 6.4MB each, xoff 6.4MB),
    // all dead before the first gather writes agg. No memset anywhere.
    ushort* agg     = (ushort*)d_ws;                 // N*DD bf16 (25.6 MB)
    ushort* xb      = agg + (size_t)NN * DD;         // N*DD bf16 (25.6 MB) -> becomes hs
    float* dinv_out = (float*)(xb + (size_t)NN * DD);
    float* dinv_in  = dinv_out + NN;
    int*   cnt      = (int*)(dinv_in + NN);          // N (cnt_total for scan)
    int*   excl     = cnt + NN;                      // N
    int*   row_st   = excl + NN;                     // N
    int*   srcs     = row_st + NN;                   // E
    int*   bsums    = srcs + EE;                     // 256
    ushort* wb1     = (ushort*)(bsums + 256);        // 128*128 bf16 (32 KB)
    ushort* wb2     = wb1 + DD * DD;                 // 128*128 bf16 (32 KB)

    unsigned char* off_u8      = (unsigned char*)agg;              // E bytes (aliased)
    unsigned int*  partial_in  = (unsigned int*)(off_u8 + EE);     // CC*NWORDS (aliased)
    unsigned int*  partial_out = partial_in + CC * NWORDS;         // CC*NWORDS (aliased)
    unsigned int*  xoff        = partial_out + CC * NWORDS;        // CC*NWORDS (aliased)

    // ---- degrees + CSR build (reused by both layers) + W conversion ----
    wconv_kernel<<<32, 256, 0, stream>>>(W1, W2, wb1, wb2);
    count_kernel<<<256, 512, 0, stream>>>(row, col, partial_out, partial_in, off_u8);
    node_kernel<<<(NWORDS + 255) / 256, 256, 0, stream>>>(partial_out, partial_in, cnt, xoff,
                                                          dinv_out, dinv_in);
    scan1_kernel<<<NB1, 256, 0, stream>>>(cnt, excl, bsums);
    scan2_kernel<<<1, 256, 0, stream>>>(bsums, NB1);
    scan3_kernel<<<(NN + 255) / 256, 256, 0, stream>>>(excl, bsums, row_st);
    fill_kernel<<<(EE + 255) / 256, 256, 0, stream>>>(row, col, row_st,
                                                      (const unsigned char*)xoff, off_u8, srcs);

    // ---- layer 1 ----
    prescale_kernel<<<(NN * 32 + 255) / 256, 256, 0, stream>>>(x, dinv_out, xb);
    gather_kernel<<<NN / 4, 256, 0, stream>>>(xb, row_st, srcs, agg);
    gemm_ep<true><<<(NTILE + 7) / 8, 256, 0, stream>>>(agg, wb1, b1, dinv_in, dinv_out, x,
                                                       /*hs=*/xb, /*out=*/nullptr);

    // ---- layer 2 ----
    gather_kernel<<<NN / 4, 256, 0, stream>>>(xb, row_st, srcs, agg);
    gemm_ep<false><<<(NTILE + 7) / 8, 256, 0, stream>>>(agg, wb2, b2, dinv_in, nullptr, nullptr,
                                                        nullptr, out);
}

// Round 9
// 274.856 us; speedup vs baseline: 1.0552x; 1.0552x over previous
//
#include <hip/hip_runtime.h>

// GCN: N=100000, E=800000, D=128, two GraphConv layers.
// R13 = exact R11 (best: 267.5us) + ONE change: gather main loop unrolled
// 4->8 edges per node (8 uint4 in flight per lane, 32/wave, ~1024/CU).
//  - R12 lesson: wave-per-node HALVED in-flight loads per CU (512->256) ->
//    +22.5us. For the latency-bound gather, outstanding loads per CU is
//    the metric, not exec-mask efficiency. This round raises it to 1024.
// Everything else byte-identical to R11 (LDS-histogram CSR build, bf16 wb
// staged to LDS in gemm, zero global atomics).

#define NN 100000
#define EE 800000
#define DD 128
#define NB1 98            // ceil(NN / 1024) blocks for scan level 1
#define NTILE (NN / 16)   // 6250 MFMA row-tiles (NN % 16 == 0)

#define CC 64             // edge chunks
#define CH (EE / CC)      // 12500 edges per chunk
#define HALF 50000        // nodes per LDS histogram (2 ranges)
#define HWORDS 12500      // packed u8 words per histogram (50KB LDS)
#define NWORDS 25000      // packed words per full node array

typedef __attribute__((ext_vector_type(8))) short short8;
typedef __attribute__((ext_vector_type(4))) float floatx4;

__device__ inline float bf2f(unsigned int u16) {
    union { unsigned int i; float f; } c;
    c.i = u16 << 16;
    return c.f;
}
__device__ inline ushort f2bf(float f) {
    union { float f; unsigned int i; } c;
    c.f = f;
    unsigned int u = c.i;
    return (ushort)((u + 0x7fffu + ((u >> 16) & 1u)) >> 16);  // RNE
}

// ---------------- chunked packed-u8 LDS histograms ----------------
__global__ __launch_bounds__(512) void count_kernel(const int* __restrict__ row,
                                                    const int* __restrict__ col,
                                                    unsigned int* __restrict__ partial_out,
                                                    unsigned int* __restrict__ partial_in,
                                                    unsigned char* __restrict__ off_u8) {
    __shared__ unsigned int h[HWORDS];
    for (int i = threadIdx.x; i < HWORDS; i += 512) h[i] = 0;
    __syncthreads();

    const int kind = blockIdx.x >> 7;          // 0 = in (col), 1 = out (row)
    const int r = (blockIdx.x >> 6) & 1;       // node range
    const int c = blockIdx.x & 63;             // edge chunk
    const int* __restrict__ idx = kind ? row : col;
    const int base = c * CH;
    const int lo = r * HALF;

    for (int t = threadIdx.x; t < CH; t += 512) {
        const int e = base + t;
        const unsigned int d = (unsigned int)(idx[e] - lo);
        if (d < (unsigned int)HALF) {
            const int sh = 8 * (d & 3);
            unsigned int old = atomicAdd(&h[d >> 2], 1u << sh);
            if (kind == 0) off_u8[e] = (unsigned char)((old >> sh) & 0xffu);
        }
    }
    __syncthreads();

    unsigned int* dst = (kind ? partial_out : partial_in) + c * NWORDS + r * HWORDS;
    for (int i = threadIdx.x; i < HWORDS; i += 512) dst[i] = h[i];
}

// ---------------- per-node: totals, dinv, per-chunk packed-u8 prefixes ----------------
__global__ __launch_bounds__(256) void node_kernel(const unsigned int* __restrict__ partial_out,
                                                   const unsigned int* __restrict__ partial_in,
                                                   int* __restrict__ cnt_total,
                                                   unsigned int* __restrict__ xoff,
                                                   float* __restrict__ dinv_out,
                                                   float* __restrict__ dinv_in) {
    const int w = blockIdx.x * 256 + threadIdx.x;
    if (w >= NWORDS) return;
    unsigned int prefix = 0;   // packed running prefix (4 nodes)
    unsigned int tot_out = 0;  // packed out-degree totals
#pragma unroll
    for (int c = 0; c < CC; ++c) {
        unsigned int v = partial_in[c * NWORDS + w];
        xoff[c * NWORDS + w] = prefix;
        prefix += v;
        tot_out += partial_out[c * NWORDS + w];
    }
    int4 ct;
    float4 fi, fo;
#pragma unroll
    for (int j = 0; j < 4; ++j) {
        int din  = (int)((prefix  >> (8 * j)) & 0xffu);
        int dout = (int)((tot_out >> (8 * j)) & 0xffu);
        ((int*)&ct)[j]   = din;
        ((float*)&fi)[j] = rsqrtf((float)max(din, 1));
        ((float*)&fo)[j] = rsqrtf((float)max(dout, 1));
    }
    ((int4*)cnt_total)[w] = ct;
    ((float4*)dinv_in)[w] = fi;
    ((float4*)dinv_out)[w] = fo;
}

// ---------------- exclusive scan of cnt_total (3-level) ----------------
__global__ __launch_bounds__(256) void scan1_kernel(const int* __restrict__ cnt,
                                                    int* __restrict__ excl,
                                                    int* __restrict__ bsums) {
    __shared__ int tmp[256];
    const int t = threadIdx.x;
    const int base = blockIdx.x * 1024 + t * 4;
    int a[4];
#pragma unroll
    for (int q = 0; q < 4; ++q) a[q] = (base + q < NN) ? cnt[base + q] : 0;
    int s = a[0] + a[1] + a[2] + a[3];
    tmp[t] = s;
    __syncthreads();
    for (int off = 1; off < 256; off <<= 1) {
        int v = 0;
        if (t >= off) v = tmp[t - off];
        __syncthreads();
        tmp[t] += v;
        __syncthreads();
    }
    int excl_s = tmp[t] - s;
    if (t == 255) bsums[blockIdx.x] = tmp[t];
    int run = excl_s;
#pragma unroll
    for (int q = 0; q < 4; ++q) {
        if (base + q < NN) excl[base + q] = run;
        run += a[q];
    }
}

__global__ __launch_bounds__(256) void scan2_kernel(int* __restrict__ bsums, int nb) {
    __shared__ int tmp[256];
    const int t = threadIdx.x;
    int s = (t < nb) ? bsums[t] : 0;
    tmp[t] = s;
    __syncthreads();
    for (int off = 1; off < 256; off <<= 1) {
        int v = 0;
        if (t >= off) v = tmp[t - off];
        __syncthreads();
        tmp[t] += v;
        __syncthreads();
    }
    if (t < nb) bsums[t] = tmp[t] - s;   // exclusive
}

__global__ __launch_bounds__(256) void scan3_kernel(const int* __restrict__ excl,
                                                    const int* __restrict__ bsums,
                                                    int* __restrict__ row_start) {
    int i = blockIdx.x * 256 + threadIdx.x;
    if (i < NN) row_start[i] = excl[i] + bsums[i >> 10];
}

// ---------------- atomic-free CSR fill ----------------
__global__ __launch_bounds__(256) void fill_kernel(const int* __restrict__ row,
                                                   const int* __restrict__ col,
                                                   const int* __restrict__ row_start,
                                                   const unsigned char* __restrict__ xoff_u8,
                                                   const unsigned char* __restrict__ off_u8,
                                                   int* __restrict__ srcs) {
    int e = blockIdx.x * 256 + threadIdx.x;
    if (e < EE) {
        const int cl = col[e];
        const int c = e / CH;                    // chunk id
        const int pos = row_start[cl] + (int)xoff_u8[(size_t)c * NN + cl] + (int)off_u8[e];
        srcs[pos] = row[e];
    }
}

// ---------------- xb = bf16(x * dinv_out) ----------------
__global__ __launch_bounds__(256) void prescale_kernel(const float* __restrict__ x,
                                                       const float* __restrict__ dinv_out,
                                                       ushort* __restrict__ xb) {
    int idx = blockIdx.x * 256 + threadIdx.x;   // one float4 per thread
    if (idx >= NN * 32) return;
    int n = idx >> 5;
    float s = dinv_out[n];
    float4 v = ((const float4*)x)[idx];
    ushort4 o;
    o.x = f2bf(v.x * s);
    o.y = f2bf(v.y * s);
    o.z = f2bf(v.z * s);
    o.w = f2bf(v.w * s);
    ((ushort4*)xb)[idx] = o;
}

// ---------------- W fp32 -> bf16 (once, both layers) ----------------
__global__ __launch_bounds__(256) void wconv_kernel(const float* __restrict__ W1,
                                                    const float* __restrict__ W2,
                                                    ushort* __restrict__ wb1,
                                                    ushort* __restrict__ wb2) {
    int i = blockIdx.x * 256 + threadIdx.x;     // one float4 per thread, 2*4096 total
    if (i >= 8192) return;
    const float* W = (i < 4096) ? W1 : W2;
    ushort* wb = (i < 4096) ? wb1 : wb2;
    int j = i & 4095;
    float4 v = ((const float4*)W)[j];
    ushort4 o;
    o.x = f2bf(v.x); o.y = f2bf(v.y); o.z = f2bf(v.z); o.w = f2bf(v.w);
    ((ushort4*)wb)[j] = o;
}

// ---------------- gather: 16 lanes/node, uint4 per lane, 8-edge main loop ----------------
__global__ __launch_bounds__(256) void gather_kernel(const ushort* __restrict__ src,
                                                     const int* __restrict__ row_start,
                                                     const int* __restrict__ srcs,
                                                     ushort* __restrict__ agg) {
    const int node = blockIdx.x * 16 + (threadIdx.x >> 4);
    const int lane = threadIdx.x & 15;
    if (node >= NN) return;
    int p = row_start[node];
    const int end = (node + 1 < NN) ? row_start[node + 1] : EE;
    float a0 = 0.f, a1 = 0.f, a2 = 0.f, a3 = 0.f;
    float a4 = 0.f, a5 = 0.f, a6 = 0.f, a7 = 0.f;

#define ACCUM(V)                                     \
    do {                                             \
        a0 += bf2f((V).x & 0xffffu);                 \
        a1 += bf2f((V).x >> 16);                     \
        a2 += bf2f((V).y & 0xffffu);                 \
        a3 += bf2f((V).y >> 16);                     \
        a4 += bf2f((V).z & 0xffffu);                 \
        a5 += bf2f((V).z >> 16);                     \
        a6 += bf2f((V).w & 0xffffu);                 \
        a7 += bf2f((V).w >> 16);                     \
    } while (0)

    for (; p + 7 < end; p += 8) {
        int s0 = srcs[p];
        int s1 = srcs[p + 1];
        int s2 = srcs[p + 2];
        int s3 = srcs[p + 3];
        int s4 = srcs[p + 4];
        int s5 = srcs[p + 5];
        int s6 = srcs[p + 6];
        int s7 = srcs[p + 7];
        uint4 v0 = ((const uint4*)(src + (size_t)s0 * DD))[lane];
        uint4 v1 = ((const uint4*)(src + (size_t)s1 * DD))[lane];
        uint4 v2 = ((const uint4*)(src + (size_t)s2 * DD))[lane];
        uint4 v3 = ((const uint4*)(src + (size_t)s3 * DD))[lane];
        uint4 v4 = ((const uint4*)(src + (size_t)s4 * DD))[lane];
        uint4 v5 = ((const uint4*)(src + (size_t)s5 * DD))[lane];
        uint4 v6 = ((const uint4*)(src + (size_t)s6 * DD))[lane];
        uint4 v7 = ((const uint4*)(src + (size_t)s7 * DD))[lane];
        ACCUM(v0); ACCUM(v1); ACCUM(v2); ACCUM(v3);
        ACCUM(v4); ACCUM(v5); ACCUM(v6); ACCUM(v7);
    }
    for (; p + 3 < end; p += 4) {
        int s0 = srcs[p];
        int s1 = srcs[p + 1];
        int s2 = srcs[p + 2];
        int s3 = srcs[p + 3];
        uint4 v0 = ((const uint4*)(src + (size_t)s0 * DD))[lane];
        uint4 v1 = ((const uint4*)(src + (size_t)s1 * DD))[lane];
        uint4 v2 = ((const uint4*)(src + (size_t)s2 * DD))[lane];
        uint4 v3 = ((const uint4*)(src + (size_t)s3 * DD))[lane];
        ACCUM(v0); ACCUM(v1); ACCUM(v2); ACCUM(v3);
    }
    for (; p < end; ++p) {
        int s0 = srcs[p];
        uint4 v0 = ((const uint4*)(src + (size_t)s0 * DD))[lane];
        ACCUM(v0);
    }
#undef ACCUM

    uint4 o;
    o.x = (unsigned int)f2bf(a0) | ((unsigned int)f2bf(a1) << 16);
    o.y = (unsigned int)f2bf(a2) | ((unsigned int)f2bf(a3) << 16);
    o.z = (unsigned int)f2bf(a4) | ((unsigned int)f2bf(a5) << 16);
    o.w = (unsigned int)f2bf(a6) | ((unsigned int)f2bf(a7) << 16);
    ((uint4*)(agg + (size_t)node * DD))[lane] = o;
}

// ---------------- MFMA bf16 GEMM + epilogue ----------------
// C[m, j] = sum_k agg[m,k] * wb[j,k]   (wb row-major [j][k] == B^T input)
// Block: 256 threads = 4 waves, each wave one 16-row tile x all 128 cols.
// wb (bf16) staged into LDS, rows padded to 136 (2-way conflict only).
template <bool L1>
__global__ __launch_bounds__(256) void gemm_ep(const ushort* __restrict__ agg,
                                               const ushort* __restrict__ wb,
                                               const float* __restrict__ bias,
                                               const float* __restrict__ dinv_in,
                                               const float* __restrict__ dinv_out,
                                               const float* __restrict__ x,
                                               ushort* __restrict__ hs,
                                               float* __restrict__ out) {
    __shared__ ushort Ws[128 * 136];
    {   // stage wb (already bf16) into LDS: 128B per thread = 8 x uint4
        int j = threadIdx.x >> 1;
        int k0 = (threadIdx.x & 1) * 64;
        const uint4* wp = (const uint4*)(wb + (size_t)j * DD + k0);
        uint4* dst = (uint4*)(Ws + j * 136 + k0);
#pragma unroll
        for (int q = 0; q < 8; ++q) dst[q] = wp[q];
    }
    __syncthreads();

    const int wave = threadIdx.x >> 6;
    const int lane = threadIdx.x & 63;
    const int tile = blockIdx.x * 4 + wave;
    if (tile >= NTILE) return;
    const int mi = lane & 15;
    const int quad = lane >> 4;
    const int m0 = tile * 16;

    floatx4 acc[8];
#pragma unroll
    for (int t = 0; t < 8; ++t) acc[t] = (floatx4){0.f, 0.f, 0.f, 0.f};

    const ushort* ap = agg + (size_t)(m0 + mi) * DD + quad * 8;
#pragma unroll
    for (int s = 0; s < 4; ++s) {
        short8 a = *(const short8*)(ap + s * 32);
#pragma unroll
        for (int t = 0; t < 8; ++t) {
            short8 b = *(const short8*)(Ws + (t * 16 + mi) * 136 + s * 32 + quad * 8);
            acc[t] = __builtin_amdgcn_mfma_f32_16x16x32_bf16(a, b, acc[t], 0, 0, 0);
        }
    }

    // C/D layout: col = lane&15, row = quad*4 + reg
    float dv[4], dov[4];
#pragma unroll
    for (int i = 0; i < 4; ++i) {
        int r = m0 + quad * 4 + i;
        dv[i] = dinv_in[r];
        if (L1) dov[i] = dinv_out[r];
    }
#pragma unroll
    for (int t = 0; t < 8; ++t) {
        int c = t * 16 + mi;
        float bv = bias[c];
#pragma unroll
        for (int i = 0; i < 4; ++i) {
            int r = m0 + quad * 4 + i;
            float o = (acc[t][i] + bv) * dv[i];
            if (L1) {
                o += x[(size_t)r * DD + c];
                o = fmaxf(o, 0.f);
                hs[(size_t)r * DD + c] = f2bf(o * dov[i]);
            } else {
                out[(size_t)r * DD + c] = o;
            }
        }
    }
}

extern "C" void kernel_launch(void* const* d_in, const int* in_sizes, int n_in,
                              void* d_out, int out_size, void* d_ws, size_t ws_size,
                              hipStream_t stream) {
    const float* x  = (const float*)d_in[0];
    const int*   ei = (const int*)d_in[1];
    const float* W1 = (const float*)d_in[2];
    const float* b1 = (const float*)d_in[3];
    const float* W2 = (const float*)d_in[4];
    const float* b2 = (const float*)d_in[5];
    float* out = (float*)d_out;

    const int* row = ei;        // edge_index[0] (source)
    const int* col = ei + EE;   // edge_index[1] (target)

    // workspace layout. The agg region (25.6MB) hosts the CSR-build
    // temporaries (off_u8 0.8MB, partial_in/out 6.4MB each, xoff 6.4MB),
    // all dead before the first gather writes agg. No memset anywhere.
    ushort* agg     = (ushort*)d_ws;                 // N*DD bf16 (25.6 MB)
    ushort* xb      = agg + (size_t)NN * DD;         // N*DD bf16 (25.6 MB) -> becomes hs
    float* dinv_out = (float*)(xb + (size_t)NN * DD);
    float* dinv_in  = dinv_out + NN;
    int*   cnt      = (int*)(dinv_in + NN);          // N (cnt_total for scan)
    int*   excl     = cnt + NN;                      // N
    int*   row_st   = excl + NN;                     // N
    int*   srcs     = row_st + NN;                   // E
    int*   bsums    = srcs + EE;                     // 256
    ushort* wb1     = (ushort*)(bsums + 256);        // 128*128 bf16 (32 KB)
    ushort* wb2     = wb1 + DD * DD;                 // 128*128 bf16 (32 KB)

    unsigned char* off_u8      = (unsigned char*)agg;              // E bytes (aliased)
    unsigned int*  partial_in  = (unsigned int*)(off_u8 + EE);     // CC*NWORDS (aliased)
    unsigned int*  partial_out = partial_in + CC * NWORDS;         // CC*NWORDS (aliased)
    unsigned int*  xoff        = partial_out + CC * NWORDS;        // CC*NWORDS (aliased)

    // ---- degrees + CSR build (reused by both layers) + W conversion ----
    wconv_kernel<<<32, 256, 0, stream>>>(W1, W2, wb1, wb2);
    count_kernel<<<256, 512, 0, stream>>>(row, col, partial_out, partial_in, off_u8);
    node_kernel<<<(NWORDS + 255) / 256, 256, 0, stream>>>(partial_out, partial_in, cnt, xoff,
                                                          dinv_out, dinv_in);
    scan1_kernel<<<NB1, 256, 0, stream>>>(cnt, excl, bsums);
    scan2_kernel<<<1, 256, 0, stream>>>(bsums, NB1);
    scan3_kernel<<<(NN + 255) / 256, 256, 0, stream>>>(excl, bsums, row_st);
    fill_kernel<<<(EE + 255) / 256, 256, 0, stream>>>(row, col, row_st,
                                                      (const unsigned char*)xoff, off_u8, srcs);

    // ---- layer 1 ----
    prescale_kernel<<<(NN * 32 + 255) / 256, 256, 0, stream>>>(x, dinv_out, xb);
    gather_kernel<<<(NN + 15) / 16, 256, 0, stream>>>(xb, row_st, srcs, agg);
    gemm_ep<true><<<(NTILE + 3) / 4, 256, 0, stream>>>(agg, wb1, b1, dinv_in, dinv_out, x,
                                                       /*hs=*/xb, /*out=*/nullptr);

    // ---- layer 2 ----
    gather_kernel<<<(NN + 15) / 16, 256, 0, stream>>>(xb, row_st, srcs, agg);
    gemm_ep<false><<<(NTILE + 3) / 4, 256, 0, stream>>>(agg, wb2, b2, dinv_in, nullptr, nullptr,
                                                        nullptr, out);
}

// Round 10
// 264.332 us; speedup vs baseline: 1.0973x; 1.0398x over previous
//
#include <hip/hip_runtime.h>

// GCN: N=100000, E=800000, D=128, two GraphConv layers.
// R14 = exact R11 compute kernels (best: 267.5us; R12/R13 established the
// gather is at its L3-throughput plateau - unroll 4 is optimal) + launch
// consolidation, 13 -> 9 launches:
//  - wconv folded into count_kernel (lanes 0-31 of each block, independent)
//  - scan3 deleted: row_start(n) = excl[n] + bsums[n>>10] inlined into
//    fill and gather (bsums 392B L1-resident; validated in R10)
//  - fill + prescale merged (disjoint block ranges; scatter-bound fill
//    overlaps streaming prescale)
// CSR build + gemm otherwise byte-identical to R11.

#define NN 100000
#define EE 800000
#define DD 128
#define NB1 98            // ceil(NN / 1024) blocks for scan level 1
#define NTILE (NN / 16)   // 6250 MFMA row-tiles (NN % 16 == 0)

#define CC 64             // edge chunks
#define CH (EE / CC)      // 12500 edges per chunk
#define HALF 50000        // nodes per LDS histogram (2 ranges)
#define HWORDS 12500      // packed u8 words per histogram (50KB LDS)
#define NWORDS 25000      // packed words per full node array

#define FB (EE / 256)     // 3125 fill blocks in the merged kernel
#define PB (NN * 32 / 256) // 12500 prescale blocks in the merged kernel

typedef __attribute__((ext_vector_type(8))) short short8;
typedef __attribute__((ext_vector_type(4))) float floatx4;

__device__ inline float bf2f(unsigned int u16) {
    union { unsigned int i; float f; } c;
    c.i = u16 << 16;
    return c.f;
}
__device__ inline ushort f2bf(float f) {
    union { float f; unsigned int i; } c;
    c.f = f;
    unsigned int u = c.i;
    return (ushort)((u + 0x7fffu + ((u >> 16) & 1u)) >> 16);  // RNE
}

// ---------------- chunked packed-u8 LDS histograms (+ embedded wconv) ----------------
// grid = 256 blocks x 512. Histogram work identical to R11. Additionally,
// lanes 0..31 of each block convert 32 float4s of W1/W2 -> bf16 wb1/wb2
// (8192 float4 total across 256 blocks; independent of histogram outputs).
__global__ __launch_bounds__(512) void count_kernel(const int* __restrict__ row,
                                                    const int* __restrict__ col,
                                                    unsigned int* __restrict__ partial_out,
                                                    unsigned int* __restrict__ partial_in,
                                                    unsigned char* __restrict__ off_u8,
                                                    const float* __restrict__ W1,
                                                    const float* __restrict__ W2,
                                                    ushort* __restrict__ wb1,
                                                    ushort* __restrict__ wb2) {
    __shared__ unsigned int h[HWORDS];
    for (int i = threadIdx.x; i < HWORDS; i += 512) h[i] = 0;
    if (threadIdx.x < 32) {   // embedded wconv: 32 float4 per block
        int i = blockIdx.x * 32 + threadIdx.x;   // 0..8191
        const float* W = (i < 4096) ? W1 : W2;
        ushort* wb = (i < 4096) ? wb1 : wb2;
        int j = i & 4095;
        float4 v = ((const float4*)W)[j];
        ushort4 o;
        o.x = f2bf(v.x); o.y = f2bf(v.y); o.z = f2bf(v.z); o.w = f2bf(v.w);
        ((ushort4*)wb)[j] = o;
    }
    __syncthreads();

    const int kind = blockIdx.x >> 7;          // 0 = in (col), 1 = out (row)
    const int r = (blockIdx.x >> 6) & 1;       // node range
    const int c = blockIdx.x & 63;             // edge chunk
    const int* __restrict__ idx = kind ? row : col;
    const int base = c * CH;
    const int lo = r * HALF;

    for (int t = threadIdx.x; t < CH; t += 512) {
        const int e = base + t;
        const unsigned int d = (unsigned int)(idx[e] - lo);
        if (d < (unsigned int)HALF) {
            const int sh = 8 * (d & 3);
            unsigned int old = atomicAdd(&h[d >> 2], 1u << sh);
            if (kind == 0) off_u8[e] = (unsigned char)((old >> sh) & 0xffu);
        }
    }
    __syncthreads();

    unsigned int* dst = (kind ? partial_out : partial_in) + c * NWORDS + r * HWORDS;
    for (int i = threadIdx.x; i < HWORDS; i += 512) dst[i] = h[i];
}

// ---------------- per-node: totals, dinv, per-chunk packed-u8 prefixes ----------------
__global__ __launch_bounds__(256) void node_kernel(const unsigned int* __restrict__ partial_out,
                                                   const unsigned int* __restrict__ partial_in,
                                                   int* __restrict__ cnt_total,
                                                   unsigned int* __restrict__ xoff,
                                                   float* __restrict__ dinv_out,
                                                   float* __restrict__ dinv_in) {
    const int w = blockIdx.x * 256 + threadIdx.x;
    if (w >= NWORDS) return;
    unsigned int prefix = 0;   // packed running prefix (4 nodes)
    unsigned int tot_out = 0;  // packed out-degree totals
#pragma unroll
    for (int c = 0; c < CC; ++c) {
        unsigned int v = partial_in[c * NWORDS + w];
        xoff[c * NWORDS + w] = prefix;
        prefix += v;
        tot_out += partial_out[c * NWORDS + w];
    }
    int4 ct;
    float4 fi, fo;
#pragma unroll
    for (int j = 0; j < 4; ++j) {
        int din  = (int)((prefix  >> (8 * j)) & 0xffu);
        int dout = (int)((tot_out >> (8 * j)) & 0xffu);
        ((int*)&ct)[j]   = din;
        ((float*)&fi)[j] = rsqrtf((float)max(din, 1));
        ((float*)&fo)[j] = rsqrtf((float)max(dout, 1));
    }
    ((int4*)cnt_total)[w] = ct;
    ((float4*)dinv_in)[w] = fi;
    ((float4*)dinv_out)[w] = fo;
}

// ---------------- exclusive scan of cnt_total (2 levels; combine inlined) ----------------
__global__ __launch_bounds__(256) void scan1_kernel(const int* __restrict__ cnt,
                                                    int* __restrict__ excl,
                                                    int* __restrict__ bsums) {
    __shared__ int tmp[256];
    const int t = threadIdx.x;
    const int base = blockIdx.x * 1024 + t * 4;
    int a[4];
#pragma unroll
    for (int q = 0; q < 4; ++q) a[q] = (base + q < NN) ? cnt[base + q] : 0;
    int s = a[0] + a[1] + a[2] + a[3];
    tmp[t] = s;
    __syncthreads();
    for (int off = 1; off < 256; off <<= 1) {
        int v = 0;
        if (t >= off) v = tmp[t - off];
        __syncthreads();
        tmp[t] += v;
        __syncthreads();
    }
    int excl_s = tmp[t] - s;
    if (t == 255) bsums[blockIdx.x] = tmp[t];
    int run = excl_s;
#pragma unroll
    for (int q = 0; q < 4; ++q) {
        if (base + q < NN) excl[base + q] = run;
        run += a[q];
    }
}

__global__ __launch_bounds__(256) void scan2_kernel(int* __restrict__ bsums, int nb) {
    __shared__ int tmp[256];
    const int t = threadIdx.x;
    int s = (t < nb) ? bsums[t] : 0;
    tmp[t] = s;
    __syncthreads();
    for (int off = 1; off < 256; off <<= 1) {
        int v = 0;
        if (t >= off) v = tmp[t - off];
        __syncthreads();
        tmp[t] += v;
        __syncthreads();
    }
    if (t < nb) bsums[t] = tmp[t] - s;   // exclusive
}

// row_start(n) == excl[n] + bsums[n >> 10]  (bsums: 392B, L1-resident)

// ---------------- merged: atomic-free CSR fill (blocks < FB) + prescale ----------------
__global__ __launch_bounds__(256) void fill_prescale_kernel(const int* __restrict__ row,
                                                            const int* __restrict__ col,
                                                            const int* __restrict__ excl,
                                                            const int* __restrict__ bsums,
                                                            const unsigned char* __restrict__ xoff_u8,
                                                            const unsigned char* __restrict__ off_u8,
                                                            int* __restrict__ srcs,
                                                            const float* __restrict__ x,
                                                            const float* __restrict__ dinv_out,
                                                            ushort* __restrict__ xb) {
    if (blockIdx.x < FB) {
        // ---- fill: one edge per thread ----
        int e = blockIdx.x * 256 + threadIdx.x;   // EE % 256 == 0
        const int cl = col[e];
        const int c = e / CH;                     // chunk id
        const int rs = excl[cl] + bsums[cl >> 10];
        srcs[rs + (int)xoff_u8[(size_t)c * NN + cl] + (int)off_u8[e]] = row[e];
    } else {
        // ---- prescale: one float4 per thread ----
        int idx = (blockIdx.x - FB) * 256 + threadIdx.x;   // NN*32 % 256 == 0
        int n = idx >> 5;
        float s = dinv_out[n];
        float4 v = ((const float4*)x)[idx];
        ushort4 o;
        o.x = f2bf(v.x * s);
        o.y = f2bf(v.y * s);
        o.z = f2bf(v.z * s);
        o.w = f2bf(v.w * s);
        ((ushort4*)xb)[idx] = o;
    }
}

// ---------------- gather: 16 lanes/node, uint4 (16B) per lane, 4-edge unroll ----------------
__global__ __launch_bounds__(256) void gather_kernel(const ushort* __restrict__ src,
                                                     const int* __restrict__ excl,
                                                     const int* __restrict__ bsums,
                                                     const int* __restrict__ srcs,
                                                     ushort* __restrict__ agg) {
    const int node = blockIdx.x * 16 + (threadIdx.x >> 4);
    const int lane = threadIdx.x & 15;
    if (node >= NN) return;
    int p = excl[node] + bsums[node >> 10];
    const int end = (node + 1 < NN) ? excl[node + 1] + bsums[(node + 1) >> 10] : EE;
    float a0 = 0.f, a1 = 0.f, a2 = 0.f, a3 = 0.f;
    float a4 = 0.f, a5 = 0.f, a6 = 0.f, a7 = 0.f;

#define ACCUM(V)                                     \
    do {                                             \
        a0 += bf2f((V).x & 0xffffu);                 \
        a1 += bf2f((V).x >> 16);                     \
        a2 += bf2f((V).y & 0xffffu);                 \
        a3 += bf2f((V).y >> 16);                     \
        a4 += bf2f((V).z & 0xffffu);                 \
        a5 += bf2f((V).z >> 16);                     \
        a6 += bf2f((V).w & 0xffffu);                 \
        a7 += bf2f((V).w >> 16);                     \
    } while (0)

    for (; p + 3 < end; p += 4) {
        int s0 = srcs[p];
        int s1 = srcs[p + 1];
        int s2 = srcs[p + 2];
        int s3 = srcs[p + 3];
        uint4 v0 = ((const uint4*)(src + (size_t)s0 * DD))[lane];
        uint4 v1 = ((const uint4*)(src + (size_t)s1 * DD))[lane];
        uint4 v2 = ((const uint4*)(src + (size_t)s2 * DD))[lane];
        uint4 v3 = ((const uint4*)(src + (size_t)s3 * DD))[lane];
        ACCUM(v0); ACCUM(v1); ACCUM(v2); ACCUM(v3);
    }
    for (; p < end; ++p) {
        int s0 = srcs[p];
        uint4 v0 = ((const uint4*)(src + (size_t)s0 * DD))[lane];
        ACCUM(v0);
    }
#undef ACCUM

    uint4 o;
    o.x = (unsigned int)f2bf(a0) | ((unsigned int)f2bf(a1) << 16);
    o.y = (unsigned int)f2bf(a2) | ((unsigned int)f2bf(a3) << 16);
    o.z = (unsigned int)f2bf(a4) | ((unsigned int)f2bf(a5) << 16);
    o.w = (unsigned int)f2bf(a6) | ((unsigned int)f2bf(a7) << 16);
    ((uint4*)(agg + (size_t)node * DD))[lane] = o;
}

// ---------------- MFMA bf16 GEMM + epilogue ----------------
// C[m, j] = sum_k agg[m,k] * wb[j,k]   (wb row-major [j][k] == B^T input)
// Block: 256 threads = 4 waves, each wave one 16-row tile x all 128 cols.
// wb (bf16) staged into LDS, rows padded to 136 (2-way conflict only).
template <bool L1>
__global__ __launch_bounds__(256) void gemm_ep(const ushort* __restrict__ agg,
                                               const ushort* __restrict__ wb,
                                               const float* __restrict__ bias,
                                               const float* __restrict__ dinv_in,
                                               const float* __restrict__ dinv_out,
                                               const float* __restrict__ x,
                                               ushort* __restrict__ hs,
                                               float* __restrict__ out) {
    __shared__ ushort Ws[128 * 136];
    {   // stage wb (already bf16) into LDS: 128B per thread = 8 x uint4
        int j = threadIdx.x >> 1;
        int k0 = (threadIdx.x & 1) * 64;
        const uint4* wp = (const uint4*)(wb + (size_t)j * DD + k0);
        uint4* dst = (uint4*)(Ws + j * 136 + k0);
#pragma unroll
        for (int q = 0; q < 8; ++q) dst[q] = wp[q];
    }
    __syncthreads();

    const int wave = threadIdx.x >> 6;
    const int lane = threadIdx.x & 63;
    const int tile = blockIdx.x * 4 + wave;
    if (tile >= NTILE) return;
    const int mi = lane & 15;
    const int quad = lane >> 4;
    const int m0 = tile * 16;

    floatx4 acc[8];
#pragma unroll
    for (int t = 0; t < 8; ++t) acc[t] = (floatx4){0.f, 0.f, 0.f, 0.f};

    const ushort* ap = agg + (size_t)(m0 + mi) * DD + quad * 8;
#pragma unroll
    for (int s = 0; s < 4; ++s) {
        short8 a = *(const short8*)(ap + s * 32);
#pragma unroll
        for (int t = 0; t < 8; ++t) {
            short8 b = *(const short8*)(Ws + (t * 16 + mi) * 136 + s * 32 + quad * 8);
            acc[t] = __builtin_amdgcn_mfma_f32_16x16x32_bf16(a, b, acc[t], 0, 0, 0);
        }
    }

    // C/D layout: col = lane&15, row = quad*4 + reg
    float dv[4], dov[4];
#pragma unroll
    for (int i = 0; i < 4; ++i) {
        int r = m0 + quad * 4 + i;
        dv[i] = dinv_in[r];
        if (L1) dov[i] = dinv_out[r];
    }
#pragma unroll
    for (int t = 0; t < 8; ++t) {
        int c = t * 16 + mi;
        float bv = bias[c];
#pragma unroll
        for (int i = 0; i < 4; ++i) {
            int r = m0 + quad * 4 + i;
            float o = (acc[t][i] + bv) * dv[i];
            if (L1) {
                o += x[(size_t)r * DD + c];
                o = fmaxf(o, 0.f);
                hs[(size_t)r * DD + c] = f2bf(o * dov[i]);
            } else {
                out[(size_t)r * DD + c] = o;
            }
        }
    }
}

extern "C" void kernel_launch(void* const* d_in, const int* in_sizes, int n_in,
                              void* d_out, int out_size, void* d_ws, size_t ws_size,
                              hipStream_t stream) {
    const float* x  = (const float*)d_in[0];
    const int*   ei = (const int*)d_in[1];
    const float* W1 = (const float*)d_in[2];
    const float* b1 = (const float*)d_in[3];
    const float* W2 = (const float*)d_in[4];
    const float* b2 = (const float*)d_in[5];
    float* out = (float*)d_out;

    const int* row = ei;        // edge_index[0] (source)
    const int* col = ei + EE;   // edge_index[1] (target)

    // workspace layout. The agg region (25.6MB) hosts the CSR-build
    // temporaries (off_u8 0.8MB, partial_in/out 6.4MB each, xoff 6.4MB),
    // all dead before the first gather writes agg. No memset anywhere.
    ushort* agg     = (ushort*)d_ws;                 // N*DD bf16 (25.6 MB)
    ushort* xb      = agg + (size_t)NN * DD;         // N*DD bf16 (25.6 MB) -> becomes hs
    float* dinv_out = (float*)(xb + (size_t)NN * DD);
    float* dinv_in  = dinv_out + NN;
    int*   cnt      = (int*)(dinv_in + NN);          // N (cnt_total for scan)
    int*   excl     = cnt + NN;                      // N
    int*   srcs     = excl + NN;                     // E
    int*   bsums    = srcs + EE;                     // 256
    ushort* wb1     = (ushort*)(bsums + 256);        // 128*128 bf16 (32 KB)
    ushort* wb2     = wb1 + DD * DD;                 // 128*128 bf16 (32 KB)

    unsigned char* off_u8      = (unsigned char*)agg;              // E bytes (aliased)
    unsigned int*  partial_in  = (unsigned int*)(off_u8 + EE);     // CC*NWORDS (aliased)
    unsigned int*  partial_out = partial_in + CC * NWORDS;         // CC*NWORDS (aliased)
    unsigned int*  xoff        = partial_out + CC * NWORDS;        // CC*NWORDS (aliased)

    // ---- CSR build (+ embedded wconv), 4 launches ----
    count_kernel<<<256, 512, 0, stream>>>(row, col, partial_out, partial_in, off_u8,
                                          W1, W2, wb1, wb2);
    node_kernel<<<(NWORDS + 255) / 256, 256, 0, stream>>>(partial_out, partial_in, cnt, xoff,
                                                          dinv_out, dinv_in);
    scan1_kernel<<<NB1, 256, 0, stream>>>(cnt, excl, bsums);
    scan2_kernel<<<1, 256, 0, stream>>>(bsums, NB1);

    // ---- fill + prescale (merged, 1 launch) ----
    fill_prescale_kernel<<<FB + PB, 256, 0, stream>>>(row, col, excl, bsums,
                                                      (const unsigned char*)xoff, off_u8, srcs,
                                                      x, dinv_out, xb);

    // ---- layer 1 ----
    gather_kernel<<<(NN + 15) / 16, 256, 0, stream>>>(xb, excl, bsums, srcs, agg);
    gemm_ep<true><<<(NTILE + 3) / 4, 256, 0, stream>>>(agg, wb1, b1, dinv_in, dinv_out, x,
                                                       /*hs=*/xb, /*out=*/nullptr);

    // ---- layer 2 ----
    gather_kernel<<<(NN + 15) / 16, 256, 0, stream>>>(xb, excl, bsums, srcs, agg);
    gemm_ep<false><<<(NTILE + 3) / 4, 256, 0, stream>>>(agg, wb2, b2, dinv_in, nullptr, nullptr,
                                                        nullptr, out);
}